// Round 9
// baseline (59.541 us; speedup 1.0000x reference)
//
#include <hip/hip_runtime.h>
#include <hip/hip_bf16.h>

// Problem constants
constexpr int B  = 4;
constexpr int N  = 10000;
constexpr int E  = 160000;
constexpr int F  = 64;     // F_IN
constexpr int DA = 128;    // D_ATT
constexpr int H  = 8;
constexpr int DK = 16;
constexpr int TOTAL = B * N;   // 40000 rows

constexpr int EPB  = 512;                   // edges per block (gather)
constexpr int NBLK = (E + EPB - 1) / EPB;   // 313 blocks per b

// prep sizes (in groups of 4 floats)
constexpr int XG = TOTAL * F / 4;           // 640000
constexpr int WG = 3 * DA * F / 4;          // 6144
constexpr int PREPBLK = (XG + WG) / 256;    // 2524 exactly

typedef __attribute__((ext_vector_type(8))) short short8v;  // 8 bf16 (4 VGPRs)
typedef __attribute__((ext_vector_type(4))) float f32x4;
typedef __attribute__((ext_vector_type(2))) float f32x2;

__device__ __forceinline__ unsigned pack_bf16(float a, float b) {
    unsigned ua = __builtin_bit_cast(unsigned, a);
    unsigned ub = __builtin_bit_cast(unsigned, b);
    ua = (ua + 0x7fffu + ((ua >> 16) & 1u)) >> 16;   // RNE
    ub = (ub + 0x7fffu + ((ub >> 16) & 1u)) >> 16;
    return ua | (ub << 16);
}
// q,k dwords = 4 fp8 covering 4 consecutive heads; accumulate into two f32x2.
__device__ __forceinline__ void fp8dot(unsigned q, unsigned k, f32x2& olo, f32x2& ohi) {
    f32x2 ql = __builtin_amdgcn_cvt_pk_f32_fp8((int)q, false);
    f32x2 qh = __builtin_amdgcn_cvt_pk_f32_fp8((int)q, true);
    f32x2 kl = __builtin_amdgcn_cvt_pk_f32_fp8((int)k, false);
    f32x2 kh = __builtin_amdgcn_cvt_pk_f32_fp8((int)k, true);
    olo += ql * kl;
    ohi += qh * kh;
}

// ---------------------------------------------------------------------------
// K0: prep — convert x and Qw/Kw/Vw to bf16 once (RNE, same rounding the
// old in-proj cvt used). Qw is pre-scaled by 0.25 (= 1/sqrt(DK), a power of
// two, so scaling commutes with bf16 rounding -> numerics identical).
// Thread = one float4 -> one uint2 (4 bf16). Fully coalesced.
// ---------------------------------------------------------------------------
__global__ __launch_bounds__(256) void prep_cvt(
    const float* __restrict__ x,
    const float* __restrict__ Qw, const float* __restrict__ Kw,
    const float* __restrict__ Vw,
    unsigned short* __restrict__ xbf, unsigned short* __restrict__ wbf)
{
    const int j = blockIdx.x * 256 + threadIdx.x;
    if (j < XG) {
        float4 v = ((const float4*)x)[j];
        ((uint2*)xbf)[j] = make_uint2(pack_bf16(v.x, v.y), pack_bf16(v.z, v.w));
    } else {
        int wj = j - XG;                       // [0, WG)
        const int mat = wj / (DA * F / 4);
        const int off = wj - mat * (DA * F / 4);
        const float* W = (mat == 0) ? Qw : (mat == 1) ? Kw : Vw;
        const float sc = (mat == 0) ? 0.25f : 1.0f;
        float4 v = ((const float4*)W)[off];
        ((uint2*)wbf)[wj] = make_uint2(pack_bf16(v.x * sc, v.y * sc),
                                       pack_bf16(v.z * sc, v.w * sc));
    }
}

// ---------------------------------------------------------------------------
// K1: MFMA projections from pre-converted bf16. grid = (625, 3): one 16-node
// tile per wave, 1875 blocks (~7/CU). Fragments are single 16B loads.
// Layout p = d*8 + h (head-transposed). q/k stored fp8 e4m3 (scale already
// folded into Qw/Qb); v stored f32 to d_out.
// ---------------------------------------------------------------------------
__global__ __launch_bounds__(256) void proj_mfma(
    const unsigned short* __restrict__ xbf, const unsigned short* __restrict__ wbf,
    const float* __restrict__ Qb, const float* __restrict__ Kb,
    const float* __restrict__ Vb,
    unsigned char* __restrict__ qws, unsigned char* __restrict__ kws,
    float* __restrict__ vout)
{
    const int t    = threadIdx.x;
    const int w    = t >> 6;        // wave 0..3
    const int lane = t & 63;
    const int tn   = lane & 15;
    const int g    = lane >> 4;     // 0..3

    const int mat = blockIdx.y;
    const unsigned short* W = wbf + (size_t)mat * DA * F;
    const float* bias = (mat == 0) ? Qb : (mat == 1) ? Kb : Vb;
    const float bsc = (mat == 0) ? 0.25f : 1.0f;   // bias scale (W pre-scaled)

    const int m0t = blockIdx.x * 64 + w * 16;

    // x fragments: one 16B load each (k-chunk j covers k = j*32 + g*8 .. +8)
    const unsigned short* xrow = xbf + (size_t)(m0t + tn) * F;
    const short8v a0 = *(const short8v*)(xrow + g * 8);
    const short8v a1 = *(const short8v*)(xrow + 32 + g * 8);

    f32x4 acc[8];
    #pragma unroll
    for (int a0t = 0; a0t < 8; ++a0t) {
        const float bb = bias[a0t * 16 + tn] * bsc;
        acc[a0t][0] = bb; acc[a0t][1] = bb;
        acc[a0t][2] = bb; acc[a0t][3] = bb;
    }
    #pragma unroll
    for (int a0t = 0; a0t < 8; ++a0t) {
        const unsigned short* wrow = W + (size_t)(a0t * 16 + tn) * F;
        short8v b0 = *(const short8v*)(wrow + g * 8);
        short8v b1 = *(const short8v*)(wrow + 32 + g * 8);
        acc[a0t] = __builtin_amdgcn_mfma_f32_16x16x32_bf16(a0, b0, acc[a0t], 0, 0, 0);
        acc[a0t] = __builtin_amdgcn_mfma_f32_16x16x32_bf16(a1, b1, acc[a0t], 0, 0, 0);
    }

    if (mat < 2) {
        unsigned char* qk_dst = (mat == 0) ? qws : kws;
        #pragma unroll
        for (int r = 0; r < 4; ++r) {
            const int node = m0t + g * 4 + r;
            unsigned u0 = (unsigned)__builtin_amdgcn_cvt_pk_fp8_f32(
                              acc[0][r], acc[1][r], 0, false);
            u0 = (unsigned)__builtin_amdgcn_cvt_pk_fp8_f32(
                              acc[2][r], acc[3][r], (int)u0, true);
            unsigned u1 = (unsigned)__builtin_amdgcn_cvt_pk_fp8_f32(
                              acc[4][r], acc[5][r], 0, false);
            u1 = (unsigned)__builtin_amdgcn_cvt_pk_fp8_f32(
                              acc[6][r], acc[7][r], (int)u1, true);
            *(uint2*)(qk_dst + (size_t)node * DA + tn * 8) = make_uint2(u0, u1);
        }
    } else {
        #pragma unroll
        for (int r = 0; r < 4; ++r) {
            const int node = m0t + g * 4 + r;
            float* vb = vout + (size_t)node * DA + tn * 8;
            *(float4*)vb       = make_float4(acc[0][r], acc[1][r], acc[2][r], acc[3][r]);
            *(float4*)(vb + 4) = make_float4(acc[4][r], acc[5][r], acc[6][r], acc[7][r]);
        }
    }
}

// ---------------------------------------------------------------------------
// K2: fp8 gather + dot -> exp(logit) + per-block sums (no-max softmax:
// logits bounded << 88). 4 lanes per edge; lane i reads bytes [16i,+16) and
// [64+16i,+16) -> one 64B line per 4-lane group per load instruction.
// Edge indices preloaded coalesced; (s,d) via shfl. Full unroll pipelines.
// grid = (B, NBLK): linear id % 4 == b -> per-XCD L2 holds one b (2.56MB).
// ---------------------------------------------------------------------------
__global__ __launch_bounds__(256) void gather_dot_sm(
    const unsigned char* __restrict__ qws, const unsigned char* __restrict__ kws,
    const int* __restrict__ edge, float* __restrict__ att,
    float* __restrict__ psum)
{
    const int b   = blockIdx.x;
    const int blk = blockIdx.y;
    const int t = threadIdx.x;
    const int w = t >> 6, lane = t & 63;
    const int g = lane >> 2, i = lane & 3;

    const unsigned char* qb = qws + (size_t)b * N * DA;
    const unsigned char* kb = kws + (size_t)b * N * DA;
    float* attb = att + (size_t)b * E * H;

    const int ew0 = blk * EPB + w * 128;   // wave's edge base (128 edges)

    // coalesced index preload (clamped; clamped values never used)
    const int i0 = min(ew0 + lane, E - 1);
    const int i1 = min(ew0 + 64 + lane, E - 1);
    const int s0p = edge[i0], s1p = edge[i1];
    const int d0p = edge[E + i0], d1p = edge[E + i1];

    float sa0 = 0.f, sa1 = 0.f;

    #pragma unroll
    for (int r = 0; r < 8; ++r) {
        const int el = ew0 + r * 16 + g;
        const bool valid = el < E;
        const int srcl = (r * 16 + g) & 63;
        const int s = __shfl((r < 4) ? s0p : s1p, srcl);
        const int d = __shfl((r < 4) ? d0p : d1p, srcl);
        const uint4* qp = (const uint4*)(qb + (size_t)s * DA) + i;
        const uint4* kp = (const uint4*)(kb + (size_t)d * DA) + i;
        uint4 q0 = qp[0], q1 = qp[4];
        uint4 k0 = kp[0], k1 = kp[4];

        f32x2 o01 = {0.f, 0.f}, o23 = {0.f, 0.f}, o45 = {0.f, 0.f}, o67 = {0.f, 0.f};
        fp8dot(q0.x, k0.x, o01, o23);
        fp8dot(q0.y, k0.y, o45, o67);
        fp8dot(q0.z, k0.z, o01, o23);
        fp8dot(q0.w, k0.w, o45, o67);
        fp8dot(q1.x, k1.x, o01, o23);
        fp8dot(q1.y, k1.y, o45, o67);
        fp8dot(q1.z, k1.z, o01, o23);
        fp8dot(q1.w, k1.w, o45, o67);

        // reduce across the 4 lanes of the edge group
        #pragma unroll
        for (int off = 1; off <= 2; off <<= 1) {
            o01[0] += __shfl_xor(o01[0], off);  o01[1] += __shfl_xor(o01[1], off);
            o23[0] += __shfl_xor(o23[0], off);  o23[1] += __shfl_xor(o23[1], off);
            o45[0] += __shfl_xor(o45[0], off);  o45[1] += __shfl_xor(o45[1], off);
            o67[0] += __shfl_xor(o67[0], off);  o67[1] += __shfl_xor(o67[1], off);
        }

        f32x2 pp = (i == 0) ? o01 : (i == 1) ? o23 : (i == 2) ? o45 : o67;
        if (valid) {
            float e0 = __expf(pp[0]), e1 = __expf(pp[1]);
            *(f32x2*)(attb + (size_t)el * H + 2 * i) = f32x2{e0, e1};
            sa0 += e0;
            sa1 += e1;
        }
    }

    // wave-level sum across the 16 groups (lanes with equal i)
    #pragma unroll
    for (int off = 4; off <= 32; off <<= 1) {
        sa0 += __shfl_xor(sa0, off);
        sa1 += __shfl_xor(sa1, off);
    }

    __shared__ float2 red[4][4];
    if (g == 0) red[w][i] = make_float2(sa0, sa1);
    __syncthreads();
    if (t < 4) {
        float s0f = 0.f, s1f = 0.f;
        #pragma unroll
        for (int ww = 0; ww < 4; ++ww) {
            float2 v = red[ww][t];
            s0f += v.x;
            s1f += v.y;
        }
        psum[((size_t)b * H + 2 * t)     * NBLK + blk] = s0f;
        psum[((size_t)b * H + 2 * t + 1) * NBLK + blk] = s1f;
    }
}

// ---------------------------------------------------------------------------
// K3: fused final+normalize. grid (B, NBLK) — block (b,blk) covers EXACTLY
// gather block (b,blk)'s chunk -> same linear block index -> same XCD ->
// att re-read is L2-hot. Redundant psum reduce (10KB, L2) then scale.
// ---------------------------------------------------------------------------
__global__ __launch_bounds__(256) void softmax_norm(
    float* __restrict__ att, const float* __restrict__ psum)
{
    const int b   = blockIdx.x;
    const int blk = blockIdx.y;
    const int t = threadIdx.x;
    const int w = t >> 6, lane = t & 63;

    __shared__ float inv[H];
    {
        const float* p0 = psum + ((size_t)b * H + 2 * w) * NBLK;
        const float* p1 = psum + ((size_t)b * H + 2 * w + 1) * NBLK;
        float s0 = 0.f, s1 = 0.f;
        for (int c = lane; c < NBLK; c += 64) {
            s0 += p0[c];
            s1 += p1[c];
        }
        #pragma unroll
        for (int off = 1; off < 64; off <<= 1) {
            s0 += __shfl_xor(s0, off);
            s1 += __shfl_xor(s1, off);
        }
        if (lane == 0) {
            inv[2 * w]     = 1.0f / s0;
            inv[2 * w + 1] = 1.0f / s1;
        }
    }
    __syncthreads();

    const int idx = blk * (EPB * H) + t * 16;   // floats within this b
    if (idx < E * H) {
        float* p = att + (size_t)b * (E * H) + idx;
        float4 v0 = *(float4*)p;
        float4 v1 = *(float4*)(p + 4);
        float4 v2 = *(float4*)(p + 8);
        float4 v3 = *(float4*)(p + 12);
        v0.x *= inv[0]; v0.y *= inv[1]; v0.z *= inv[2]; v0.w *= inv[3];
        v1.x *= inv[4]; v1.y *= inv[5]; v1.z *= inv[6]; v1.w *= inv[7];
        v2.x *= inv[0]; v2.y *= inv[1]; v2.z *= inv[2]; v2.w *= inv[3];
        v3.x *= inv[4]; v3.y *= inv[5]; v3.z *= inv[6]; v3.w *= inv[7];
        *(float4*)p        = v0;
        *(float4*)(p + 4)  = v1;
        *(float4*)(p + 8)  = v2;
        *(float4*)(p + 12) = v3;
    }
}

extern "C" void kernel_launch(void* const* d_in, const int* in_sizes, int n_in,
                              void* d_out, int out_size, void* d_ws, size_t ws_size,
                              hipStream_t stream)
{
    const float* x  = (const float*)d_in[0];
    const float* Qw = (const float*)d_in[1];
    const float* Qb = (const float*)d_in[2];
    const float* Kw = (const float*)d_in[3];
    const float* Kb = (const float*)d_in[4];
    const float* Vw = (const float*)d_in[5];
    const float* Vb = (const float*)d_in[6];
    const int*   edge = (const int*)d_in[7];

    float* out  = (float*)d_out;
    float* att  = out;                                // B*E*H
    float* vout = out + (size_t)B * E * H;            // B*N*DK*H

    char* w = (char*)d_ws;
    unsigned char*  qws = (unsigned char*)w;                          // 5.12 MB fp8
    unsigned char*  kws = qws + (size_t)B * N * DA;                   // 5.12 MB fp8
    unsigned short* xbf = (unsigned short*)(w + 2 * (size_t)B * N * DA);  // 5.12 MB bf16
    unsigned short* wbf = xbf + (size_t)TOTAL * F;                    // 48 KB bf16
    float* psum = (float*)(wbf + 3 * DA * F);                         // 40 KB

    hipLaunchKernelGGL(prep_cvt, dim3(PREPBLK), dim3(256), 0, stream,
                       x, Qw, Kw, Vw, xbf, wbf);
    hipLaunchKernelGGL(proj_mfma, dim3(TOTAL / 64, 3), dim3(256), 0, stream,
                       xbf, wbf, Qb, Kb, Vb, qws, kws, vout);
    hipLaunchKernelGGL(gather_dot_sm, dim3(B, NBLK), dim3(256), 0, stream,
                       qws, kws, edge, att, psum);
    hipLaunchKernelGGL(softmax_norm, dim3(B, NBLK), dim3(256), 0, stream,
                       att, psum);
}

// Round 10
// 47.712 us; speedup vs baseline: 1.2479x; 1.2479x over previous
//
#include <hip/hip_runtime.h>
#include <hip/hip_bf16.h>

// Problem constants
constexpr int B  = 4;
constexpr int N  = 10000;
constexpr int E  = 160000;
constexpr int F  = 64;     // F_IN
constexpr int DA = 128;    // D_ATT
constexpr int H  = 8;
constexpr int DK = 16;
constexpr int TOTAL = B * N;   // 40000 rows

constexpr int EPB  = 512;                   // edges per block (gather)
constexpr int NBLK = (E + EPB - 1) / EPB;   // 313 blocks per b

// prep sizes (in groups of 4 floats)
constexpr int XG = TOTAL * F / 4;           // 640000
constexpr int WG = 3 * DA * F / 4;          // 6144
constexpr int PREPBLK = (XG + WG) / 256;    // 2524 exactly

typedef __attribute__((ext_vector_type(8))) short short8v;  // 8 bf16 (4 VGPRs)
typedef __attribute__((ext_vector_type(4))) float f32x4;
typedef __attribute__((ext_vector_type(2))) float f32x2;

__device__ __forceinline__ unsigned pack_bf16(float a, float b) {
    unsigned ua = __builtin_bit_cast(unsigned, a);
    unsigned ub = __builtin_bit_cast(unsigned, b);
    ua = (ua + 0x7fffu + ((ua >> 16) & 1u)) >> 16;   // RNE
    ub = (ub + 0x7fffu + ((ub >> 16) & 1u)) >> 16;
    return ua | (ub << 16);
}
// q,k dwords = 4 fp8 covering 4 consecutive heads; accumulate into two f32x2.
__device__ __forceinline__ void fp8dot(unsigned q, unsigned k, f32x2& olo, f32x2& ohi) {
    f32x2 ql = __builtin_amdgcn_cvt_pk_f32_fp8((int)q, false);
    f32x2 qh = __builtin_amdgcn_cvt_pk_f32_fp8((int)q, true);
    f32x2 kl = __builtin_amdgcn_cvt_pk_f32_fp8((int)k, false);
    f32x2 kh = __builtin_amdgcn_cvt_pk_f32_fp8((int)k, true);
    olo += ql * kl;
    ohi += qh * kh;
}

// ---------------------------------------------------------------------------
// K0: prep — convert x and Qw/Kw/Vw to bf16 once (RNE). Qw pre-scaled by
// 0.25 (= 1/sqrt(DK), pow2 -> commutes with rounding). Fully coalesced.
// ---------------------------------------------------------------------------
__global__ __launch_bounds__(256) void prep_cvt(
    const float* __restrict__ x,
    const float* __restrict__ Qw, const float* __restrict__ Kw,
    const float* __restrict__ Vw,
    unsigned short* __restrict__ xbf, unsigned short* __restrict__ wbf)
{
    const int j = blockIdx.x * 256 + threadIdx.x;
    if (j < XG) {
        float4 v = ((const float4*)x)[j];
        ((uint2*)xbf)[j] = make_uint2(pack_bf16(v.x, v.y), pack_bf16(v.z, v.w));
    } else {
        int wj = j - XG;                       // [0, WG)
        const int mat = wj / (DA * F / 4);
        const int off = wj - mat * (DA * F / 4);
        const float* W = (mat == 0) ? Qw : (mat == 1) ? Kw : Vw;
        const float sc = (mat == 0) ? 0.25f : 1.0f;
        float4 v = ((const float4*)W)[off];
        ((uint2*)wbf)[wj] = make_uint2(pack_bf16(v.x * sc, v.y * sc),
                                       pack_bf16(v.z * sc, v.w * sc));
    }
}

// ---------------------------------------------------------------------------
// K1: MFMA projections, W staged in LDS. grid = (625, 3). Per block: stage
// this mat's 16KB bf16 W into LDS (XOR-swizzled byte^=((row&7)<<4) vs the
// 16-way ds_read_b128 bank conflict of a [row][128B] layout), then each wave
// does one 16-node tile: 2 x-loads (global) + 16 ds_read W-frags + 16 MFMA.
// Layout p = d*8 + h. q/k stored fp8 e4m3 (scale folded); v f32 to d_out.
// ---------------------------------------------------------------------------
__global__ __launch_bounds__(256) void proj_mfma(
    const unsigned short* __restrict__ xbf, const unsigned short* __restrict__ wbf,
    const float* __restrict__ Qb, const float* __restrict__ Kb,
    const float* __restrict__ Vb,
    unsigned char* __restrict__ qws, unsigned char* __restrict__ kws,
    float* __restrict__ vout)
{
    __shared__ unsigned char wlds[DA * F * 2];   // 16 KB, swizzled

    const int t = threadIdx.x;
    const int mat = blockIdx.y;

    // stage: 4 chunks of 4KB, coalesced global load, swizzled ds_write
    {
        const unsigned char* src = (const unsigned char*)wbf + (size_t)mat * DA * F * 2;
        #pragma unroll
        for (int j = 0; j < 4; ++j) {
            const int A = j * 4096 + t * 16;
            uint4 v = *(const uint4*)(src + A);
            *(uint4*)(wlds + (A ^ (((A >> 7) & 7) << 4))) = v;
        }
    }
    __syncthreads();

    const int w = t >> 6, lane = t & 63;
    const int tn = lane & 15, g = lane >> 4;

    const int m0t = blockIdx.x * 64 + w * 16;

    // x fragments: one 16B load each
    const unsigned short* xrow = xbf + (size_t)(m0t + tn) * F;
    const short8v a0 = *(const short8v*)(xrow + g * 8);
    const short8v a1 = *(const short8v*)(xrow + 32 + g * 8);

    const float* bias = (mat == 0) ? Qb : (mat == 1) ? Kb : Vb;
    const float bsc = (mat == 0) ? 0.25f : 1.0f;   // bias scale (W pre-scaled)

    f32x4 acc[8];
    #pragma unroll
    for (int a0t = 0; a0t < 8; ++a0t) {
        const float bb = bias[a0t * 16 + tn] * bsc;
        acc[a0t][0] = bb; acc[a0t][1] = bb;
        acc[a0t][2] = bb; acc[a0t][3] = bb;
    }

    const int sw = (tn & 7) << 4;    // (row&7)<<4 ; row = a0t*16+tn -> row&7 = tn&7
    #pragma unroll
    for (int a0t = 0; a0t < 8; ++a0t) {
        const int rowb = (a0t * 16 + tn) * 128;
        short8v b0 = *(const short8v*)(wlds + ((rowb + g * 16) ^ sw));
        short8v b1 = *(const short8v*)(wlds + ((rowb + 64 + g * 16) ^ sw));
        acc[a0t] = __builtin_amdgcn_mfma_f32_16x16x32_bf16(a0, b0, acc[a0t], 0, 0, 0);
        acc[a0t] = __builtin_amdgcn_mfma_f32_16x16x32_bf16(a1, b1, acc[a0t], 0, 0, 0);
    }

    if (mat < 2) {
        unsigned char* qk_dst = (mat == 0) ? qws : kws;
        #pragma unroll
        for (int r = 0; r < 4; ++r) {
            const int node = m0t + g * 4 + r;
            unsigned u0 = (unsigned)__builtin_amdgcn_cvt_pk_fp8_f32(
                              acc[0][r], acc[1][r], 0, false);
            u0 = (unsigned)__builtin_amdgcn_cvt_pk_fp8_f32(
                              acc[2][r], acc[3][r], (int)u0, true);
            unsigned u1 = (unsigned)__builtin_amdgcn_cvt_pk_fp8_f32(
                              acc[4][r], acc[5][r], 0, false);
            u1 = (unsigned)__builtin_amdgcn_cvt_pk_fp8_f32(
                              acc[6][r], acc[7][r], (int)u1, true);
            *(uint2*)(qk_dst + (size_t)node * DA + tn * 8) = make_uint2(u0, u1);
        }
    } else {
        #pragma unroll
        for (int r = 0; r < 4; ++r) {
            const int node = m0t + g * 4 + r;
            float* vb = vout + (size_t)node * DA + tn * 8;
            *(float4*)vb       = make_float4(acc[0][r], acc[1][r], acc[2][r], acc[3][r]);
            *(float4*)(vb + 4) = make_float4(acc[4][r], acc[5][r], acc[6][r], acc[7][r]);
        }
    }
}

// ---------------------------------------------------------------------------
// K2: fp8 gather + dot -> exp(logit) + per-block sums (no-max softmax:
// logits bounded << 88). 4 lanes per edge; lane i reads bytes [16i,+16) and
// [64+16i,+16) -> one 64B line per 4-lane group per load instruction.
// Edge indices preloaded coalesced; (s,d) via shfl. Full unroll pipelines.
// grid = (B, NBLK): linear id % 4 == b -> per-XCD L2 holds one b (2.56MB).
// ---------------------------------------------------------------------------
__global__ __launch_bounds__(256) void gather_dot_sm(
    const unsigned char* __restrict__ qws, const unsigned char* __restrict__ kws,
    const int* __restrict__ edge, float* __restrict__ att,
    float* __restrict__ psum)
{
    const int b   = blockIdx.x;
    const int blk = blockIdx.y;
    const int t = threadIdx.x;
    const int w = t >> 6, lane = t & 63;
    const int g = lane >> 2, i = lane & 3;

    const unsigned char* qb = qws + (size_t)b * N * DA;
    const unsigned char* kb = kws + (size_t)b * N * DA;
    float* attb = att + (size_t)b * E * H;

    const int ew0 = blk * EPB + w * 128;   // wave's edge base (128 edges)

    // coalesced index preload (clamped; clamped values never used)
    const int i0 = min(ew0 + lane, E - 1);
    const int i1 = min(ew0 + 64 + lane, E - 1);
    const int s0p = edge[i0], s1p = edge[i1];
    const int d0p = edge[E + i0], d1p = edge[E + i1];

    float sa0 = 0.f, sa1 = 0.f;

    #pragma unroll
    for (int r = 0; r < 8; ++r) {
        const int el = ew0 + r * 16 + g;
        const bool valid = el < E;
        const int srcl = (r * 16 + g) & 63;
        const int s = __shfl((r < 4) ? s0p : s1p, srcl);
        const int d = __shfl((r < 4) ? d0p : d1p, srcl);
        const uint4* qp = (const uint4*)(qb + (size_t)s * DA) + i;
        const uint4* kp = (const uint4*)(kb + (size_t)d * DA) + i;
        uint4 q0 = qp[0], q1 = qp[4];
        uint4 k0 = kp[0], k1 = kp[4];

        f32x2 o01 = {0.f, 0.f}, o23 = {0.f, 0.f}, o45 = {0.f, 0.f}, o67 = {0.f, 0.f};
        fp8dot(q0.x, k0.x, o01, o23);
        fp8dot(q0.y, k0.y, o45, o67);
        fp8dot(q0.z, k0.z, o01, o23);
        fp8dot(q0.w, k0.w, o45, o67);
        fp8dot(q1.x, k1.x, o01, o23);
        fp8dot(q1.y, k1.y, o45, o67);
        fp8dot(q1.z, k1.z, o01, o23);
        fp8dot(q1.w, k1.w, o45, o67);

        // reduce across the 4 lanes of the edge group
        #pragma unroll
        for (int off = 1; off <= 2; off <<= 1) {
            o01[0] += __shfl_xor(o01[0], off);  o01[1] += __shfl_xor(o01[1], off);
            o23[0] += __shfl_xor(o23[0], off);  o23[1] += __shfl_xor(o23[1], off);
            o45[0] += __shfl_xor(o45[0], off);  o45[1] += __shfl_xor(o45[1], off);
            o67[0] += __shfl_xor(o67[0], off);  o67[1] += __shfl_xor(o67[1], off);
        }

        f32x2 pp = (i == 0) ? o01 : (i == 1) ? o23 : (i == 2) ? o45 : o67;
        if (valid) {
            float e0 = __expf(pp[0]), e1 = __expf(pp[1]);
            *(f32x2*)(attb + (size_t)el * H + 2 * i) = f32x2{e0, e1};
            sa0 += e0;
            sa1 += e1;
        }
    }

    // wave-level sum across the 16 groups (lanes with equal i)
    #pragma unroll
    for (int off = 4; off <= 32; off <<= 1) {
        sa0 += __shfl_xor(sa0, off);
        sa1 += __shfl_xor(sa1, off);
    }

    __shared__ float2 red[4][4];
    if (g == 0) red[w][i] = make_float2(sa0, sa1);
    __syncthreads();
    if (t < 4) {
        float s0f = 0.f, s1f = 0.f;
        #pragma unroll
        for (int ww = 0; ww < 4; ++ww) {
            float2 v = red[ww][t];
            s0f += v.x;
            s1f += v.y;
        }
        psum[((size_t)b * H + 2 * t)     * NBLK + blk] = s0f;
        psum[((size_t)b * H + 2 * t + 1) * NBLK + blk] = s1f;
    }
}

// ---------------------------------------------------------------------------
// K3: fused final+normalize. grid (B, NBLK) — block (b,blk) covers EXACTLY
// gather block (b,blk)'s chunk -> same linear block index -> same XCD ->
// att re-read is L2-hot. Redundant psum reduce (10KB, L2) then scale.
// ---------------------------------------------------------------------------
__global__ __launch_bounds__(256) void softmax_norm(
    float* __restrict__ att, const float* __restrict__ psum)
{
    const int b   = blockIdx.x;
    const int blk = blockIdx.y;
    const int t = threadIdx.x;
    const int w = t >> 6, lane = t & 63;

    __shared__ float inv[H];
    {
        const float* p0 = psum + ((size_t)b * H + 2 * w) * NBLK;
        const float* p1 = psum + ((size_t)b * H + 2 * w + 1) * NBLK;
        float s0 = 0.f, s1 = 0.f;
        for (int c = lane; c < NBLK; c += 64) {
            s0 += p0[c];
            s1 += p1[c];
        }
        #pragma unroll
        for (int off = 1; off < 64; off <<= 1) {
            s0 += __shfl_xor(s0, off);
            s1 += __shfl_xor(s1, off);
        }
        if (lane == 0) {
            inv[2 * w]     = 1.0f / s0;
            inv[2 * w + 1] = 1.0f / s1;
        }
    }
    __syncthreads();

    const int idx = blk * (EPB * H) + t * 16;   // floats within this b
    if (idx < E * H) {
        float* p = att + (size_t)b * (E * H) + idx;
        float4 v0 = *(float4*)p;
        float4 v1 = *(float4*)(p + 4);
        float4 v2 = *(float4*)(p + 8);
        float4 v3 = *(float4*)(p + 12);
        v0.x *= inv[0]; v0.y *= inv[1]; v0.z *= inv[2]; v0.w *= inv[3];
        v1.x *= inv[4]; v1.y *= inv[5]; v1.z *= inv[6]; v1.w *= inv[7];
        v2.x *= inv[0]; v2.y *= inv[1]; v2.z *= inv[2]; v2.w *= inv[3];
        v3.x *= inv[4]; v3.y *= inv[5]; v3.z *= inv[6]; v3.w *= inv[7];
        *(float4*)p        = v0;
        *(float4*)(p + 4)  = v1;
        *(float4*)(p + 8)  = v2;
        *(float4*)(p + 12) = v3;
    }
}

extern "C" void kernel_launch(void* const* d_in, const int* in_sizes, int n_in,
                              void* d_out, int out_size, void* d_ws, size_t ws_size,
                              hipStream_t stream)
{
    const float* x  = (const float*)d_in[0];
    const float* Qw = (const float*)d_in[1];
    const float* Qb = (const float*)d_in[2];
    const float* Kw = (const float*)d_in[3];
    const float* Kb = (const float*)d_in[4];
    const float* Vw = (const float*)d_in[5];
    const float* Vb = (const float*)d_in[6];
    const int*   edge = (const int*)d_in[7];

    float* out  = (float*)d_out;
    float* att  = out;                                // B*E*H
    float* vout = out + (size_t)B * E * H;            // B*N*DK*H

    char* w = (char*)d_ws;
    unsigned char*  qws = (unsigned char*)w;                          // 5.12 MB fp8
    unsigned char*  kws = qws + (size_t)B * N * DA;                   // 5.12 MB fp8
    unsigned short* xbf = (unsigned short*)(w + 2 * (size_t)B * N * DA);  // 5.12 MB bf16
    unsigned short* wbf = xbf + (size_t)TOTAL * F;                    // 48 KB bf16
    float* psum = (float*)(wbf + 3 * DA * F);                         // 40 KB

    hipLaunchKernelGGL(prep_cvt, dim3(PREPBLK), dim3(256), 0, stream,
                       x, Qw, Kw, Vw, xbf, wbf);
    hipLaunchKernelGGL(proj_mfma, dim3(TOTAL / 64, 3), dim3(256), 0, stream,
                       xbf, wbf, Qb, Kb, Vb, qws, kws, vout);
    hipLaunchKernelGGL(gather_dot_sm, dim3(B, NBLK), dim3(256), 0, stream,
                       qws, kws, edge, att, psum);
    hipLaunchKernelGGL(softmax_norm, dim3(B, NBLK), dim3(256), 0, stream,
                       att, psum);
}

// Round 11
// 46.897 us; speedup vs baseline: 1.2696x; 1.0174x over previous
//
#include <hip/hip_runtime.h>
#include <hip/hip_bf16.h>

// Problem constants
constexpr int B  = 4;
constexpr int N  = 10000;
constexpr int E  = 160000;
constexpr int F  = 64;     // F_IN
constexpr int DA = 128;    // D_ATT
constexpr int H  = 8;
constexpr int DK = 16;
constexpr int TOTAL = B * N;   // 40000 rows

constexpr int EPB  = 256;          // edges per block (gather)
constexpr int NBLK = E / EPB;      // 625 blocks per b (exact)

typedef __attribute__((ext_vector_type(8))) short short8v;  // 8 bf16 (4 VGPRs)
typedef __attribute__((ext_vector_type(4))) float f32x4;
typedef __attribute__((ext_vector_type(2))) float f32x2;

__device__ __forceinline__ unsigned pack_bf16(float a, float b) {
    unsigned ua = __builtin_bit_cast(unsigned, a);
    unsigned ub = __builtin_bit_cast(unsigned, b);
    ua = (ua + 0x7fffu + ((ua >> 16) & 1u)) >> 16;   // RNE
    ub = (ub + 0x7fffu + ((ub >> 16) & 1u)) >> 16;
    return ua | (ub << 16);
}
__device__ __forceinline__ short8v cvt8(float4 a, float4 b) {
    union { unsigned u[4]; short8v s; } r;
    r.u[0] = pack_bf16(a.x, a.y);
    r.u[1] = pack_bf16(a.z, a.w);
    r.u[2] = pack_bf16(b.x, b.y);
    r.u[3] = pack_bf16(b.z, b.w);
    return r.s;
}
// q,k dwords = 4 fp8 covering 4 consecutive heads; accumulate into two f32x2.
__device__ __forceinline__ void fp8dot(unsigned q, unsigned k, f32x2& olo, f32x2& ohi) {
    f32x2 ql = __builtin_amdgcn_cvt_pk_f32_fp8((int)q, false);
    f32x2 qh = __builtin_amdgcn_cvt_pk_f32_fp8((int)q, true);
    f32x2 kl = __builtin_amdgcn_cvt_pk_f32_fp8((int)k, false);
    f32x2 kh = __builtin_amdgcn_cvt_pk_f32_fp8((int)k, true);
    olo += ql * kl;
    ohi += qh * kh;
}

// ---------------------------------------------------------------------------
// K1: MFMA projections, ALL 3 mats per block. grid = 625 blocks x 64 nodes.
// Stage: Qw/Kw/Vw f32 -> bf16 (Qw pre-scaled 0.25 = 1/sqrt(DK), pow2 so
// commutes with RNE) into 48KB LDS, XOR-swizzled byte^=((row&7)<<4) vs the
// 16-way ds_read_b128 conflict of [row][128B]. Per staging chunk j the mat
// (=j/4) and scale are compile-time. Then per wave: x read ONCE as f32 ->
// bf16 frags, 3 x (8 bias + 16 ds_read + 16 MFMA + stores) straight-line.
// 48KB -> 3 blocks/CU; 625 blocks < 768 resident slots -> single pass.
// Layout p = d*8 + h. q/k stored fp8 e4m3 (scale folded); v f32 to d_out.
// ---------------------------------------------------------------------------
__global__ __launch_bounds__(256) void proj_mfma(
    const float* __restrict__ x,
    const float* __restrict__ Qw, const float* __restrict__ Kw,
    const float* __restrict__ Vw,
    const float* __restrict__ Qb, const float* __restrict__ Kb,
    const float* __restrict__ Vb,
    unsigned char* __restrict__ qws, unsigned char* __restrict__ kws,
    float* __restrict__ vout)
{
    __shared__ unsigned char wlds[3 * DA * F * 2];   // 48 KB, swizzled

    const int t = threadIdx.x;

    // stage+convert: 12 chunks of 4KB (bf16 bytes); mat = j/4 compile-time
    #pragma unroll
    for (int j = 0; j < 12; ++j) {
        const float* W = (j < 4) ? Qw : (j < 8) ? Kw : Vw;
        const float sc = (j < 4) ? 0.25f : 1.0f;
        const int A = j * 4096 + t * 16;              // byte offset, bf16 image
        const int foff = (A - (j / 4) * 16384) / 4;   // f32 element offset
        const float4* s4 = (const float4*)(W + foff * 2);
        float4 v0 = s4[0], v1 = s4[1];
        uint4 v;
        v.x = pack_bf16(v0.x * sc, v0.y * sc);
        v.y = pack_bf16(v0.z * sc, v0.w * sc);
        v.z = pack_bf16(v1.x * sc, v1.y * sc);
        v.w = pack_bf16(v1.z * sc, v1.w * sc);
        *(uint4*)(wlds + (A ^ (((A >> 7) & 7) << 4))) = v;
    }
    __syncthreads();

    const int w = t >> 6, lane = t & 63;
    const int tn = lane & 15, g = lane >> 4;

    const int m0t = blockIdx.x * 64 + w * 16;

    // x fragments: read f32, convert once, reuse for all 3 mats
    const float4* xr = (const float4*)(x + (size_t)(m0t + tn) * F);
    const short8v a0 = cvt8(xr[g * 2],     xr[g * 2 + 1]);
    const short8v a1 = cvt8(xr[8 + g * 2], xr[8 + g * 2 + 1]);

    const int sw = (tn & 7) << 4;    // (row&7)<<4 ; row = a0t*16+tn -> row&7 = tn&7

    #pragma unroll
    for (int mat = 0; mat < 3; ++mat) {
        const float* bias = (mat == 0) ? Qb : (mat == 1) ? Kb : Vb;
        const float bsc = (mat == 0) ? 0.25f : 1.0f;
        const unsigned char* wm = wlds + mat * (DA * F * 2);

        f32x4 acc[8];
        #pragma unroll
        for (int a0t = 0; a0t < 8; ++a0t) {
            const float bb = bias[a0t * 16 + tn] * bsc;
            acc[a0t][0] = bb; acc[a0t][1] = bb;
            acc[a0t][2] = bb; acc[a0t][3] = bb;
        }
        #pragma unroll
        for (int a0t = 0; a0t < 8; ++a0t) {
            const int rowb = (a0t * 16 + tn) * 128;
            short8v b0 = *(const short8v*)(wm + ((rowb + g * 16) ^ sw));
            short8v b1 = *(const short8v*)(wm + ((rowb + 64 + g * 16) ^ sw));
            acc[a0t] = __builtin_amdgcn_mfma_f32_16x16x32_bf16(a0, b0, acc[a0t], 0, 0, 0);
            acc[a0t] = __builtin_amdgcn_mfma_f32_16x16x32_bf16(a1, b1, acc[a0t], 0, 0, 0);
        }

        if (mat < 2) {
            unsigned char* qk_dst = (mat == 0) ? qws : kws;
            #pragma unroll
            for (int r = 0; r < 4; ++r) {
                const int node = m0t + g * 4 + r;
                unsigned u0 = (unsigned)__builtin_amdgcn_cvt_pk_fp8_f32(
                                  acc[0][r], acc[1][r], 0, false);
                u0 = (unsigned)__builtin_amdgcn_cvt_pk_fp8_f32(
                                  acc[2][r], acc[3][r], (int)u0, true);
                unsigned u1 = (unsigned)__builtin_amdgcn_cvt_pk_fp8_f32(
                                  acc[4][r], acc[5][r], 0, false);
                u1 = (unsigned)__builtin_amdgcn_cvt_pk_fp8_f32(
                                  acc[6][r], acc[7][r], (int)u1, true);
                *(uint2*)(qk_dst + (size_t)node * DA + tn * 8) = make_uint2(u0, u1);
            }
        } else {
            #pragma unroll
            for (int r = 0; r < 4; ++r) {
                const int node = m0t + g * 4 + r;
                float* vb = vout + (size_t)node * DA + tn * 8;
                *(float4*)vb       = make_float4(acc[0][r], acc[1][r], acc[2][r], acc[3][r]);
                *(float4*)(vb + 4) = make_float4(acc[4][r], acc[5][r], acc[6][r], acc[7][r]);
            }
        }
    }
}

// ---------------------------------------------------------------------------
// K2: fp8 gather + dot -> exp(logit) + per-block sums (no-max softmax:
// logits bounded << 88). 4 lanes per edge; lane i reads bytes [16i,+16) and
// [64+16i,+16) -> one 64B line per 4-lane group per load instruction.
// EPB=256: 2500 blocks -> 8 blocks/CU resident = 8 waves/SIMD (vs 4.9 at
// EPB=512) for latency hiding; 64 edges/wave = ONE coalesced index preload,
// (s,d) via shfl; 4 fully-unrolled rounds; E = 625*256 -> no bounds checks.
// grid = (B, NBLK): linear id % 4 == b -> per-XCD L2 holds one b (2.56MB).
// ---------------------------------------------------------------------------
__global__ __launch_bounds__(256) void gather_dot_sm(
    const unsigned char* __restrict__ qws, const unsigned char* __restrict__ kws,
    const int* __restrict__ edge, float* __restrict__ att,
    float* __restrict__ psum)
{
    const int b   = blockIdx.x;
    const int blk = blockIdx.y;
    const int t = threadIdx.x;
    const int w = t >> 6, lane = t & 63;
    const int g = lane >> 2, i = lane & 3;

    const unsigned char* qb = qws + (size_t)b * N * DA;
    const unsigned char* kb = kws + (size_t)b * N * DA;
    float* attb = att + (size_t)b * E * H;

    const int ew0 = blk * EPB + w * 64;     // wave's edge base (64 edges)

    // coalesced index preload: exactly this wave's 64 edges
    const int i0 = ew0 + lane;
    const int s0p = edge[i0];
    const int d0p = edge[E + i0];

    float sa0 = 0.f, sa1 = 0.f;

    #pragma unroll
    for (int r = 0; r < 4; ++r) {
        const int el = ew0 + r * 16 + g;
        const int srcl = r * 16 + g;
        const int s = __shfl(s0p, srcl);
        const int d = __shfl(d0p, srcl);
        const uint4* qp = (const uint4*)(qb + (size_t)s * DA) + i;
        const uint4* kp = (const uint4*)(kb + (size_t)d * DA) + i;
        uint4 q0 = qp[0], q1 = qp[4];
        uint4 k0 = kp[0], k1 = kp[4];

        f32x2 o01 = {0.f, 0.f}, o23 = {0.f, 0.f}, o45 = {0.f, 0.f}, o67 = {0.f, 0.f};
        fp8dot(q0.x, k0.x, o01, o23);
        fp8dot(q0.y, k0.y, o45, o67);
        fp8dot(q0.z, k0.z, o01, o23);
        fp8dot(q0.w, k0.w, o45, o67);
        fp8dot(q1.x, k1.x, o01, o23);
        fp8dot(q1.y, k1.y, o45, o67);
        fp8dot(q1.z, k1.z, o01, o23);
        fp8dot(q1.w, k1.w, o45, o67);

        // reduce across the 4 lanes of the edge group
        #pragma unroll
        for (int off = 1; off <= 2; off <<= 1) {
            o01[0] += __shfl_xor(o01[0], off);  o01[1] += __shfl_xor(o01[1], off);
            o23[0] += __shfl_xor(o23[0], off);  o23[1] += __shfl_xor(o23[1], off);
            o45[0] += __shfl_xor(o45[0], off);  o45[1] += __shfl_xor(o45[1], off);
            o67[0] += __shfl_xor(o67[0], off);  o67[1] += __shfl_xor(o67[1], off);
        }

        f32x2 pp = (i == 0) ? o01 : (i == 1) ? o23 : (i == 2) ? o45 : o67;
        float e0 = __expf(pp[0]), e1 = __expf(pp[1]);
        *(f32x2*)(attb + (size_t)el * H + 2 * i) = f32x2{e0, e1};
        sa0 += e0;
        sa1 += e1;
    }

    // wave-level sum across the 16 groups (lanes with equal i)
    #pragma unroll
    for (int off = 4; off <= 32; off <<= 1) {
        sa0 += __shfl_xor(sa0, off);
        sa1 += __shfl_xor(sa1, off);
    }

    __shared__ float2 red[4][4];
    if (g == 0) red[w][i] = make_float2(sa0, sa1);
    __syncthreads();
    if (t < 4) {
        float s0f = 0.f, s1f = 0.f;
        #pragma unroll
        for (int ww = 0; ww < 4; ++ww) {
            float2 v = red[ww][t];
            s0f += v.x;
            s1f += v.y;
        }
        psum[((size_t)b * H + 2 * t)     * NBLK + blk] = s0f;
        psum[((size_t)b * H + 2 * t + 1) * NBLK + blk] = s1f;
    }
}

// ---------------------------------------------------------------------------
// K3: fused final+normalize. grid (B, NBLK) — block (b,blk) covers EXACTLY
// gather block (b,blk)'s 2048-float chunk -> same linear block index ->
// same XCD -> att re-read is L2-hot. Redundant psum reduce (20KB, L2),
// then scale; thread = one edge (8 floats).
// ---------------------------------------------------------------------------
__global__ __launch_bounds__(256) void softmax_norm(
    float* __restrict__ att, const float* __restrict__ psum)
{
    const int b   = blockIdx.x;
    const int blk = blockIdx.y;
    const int t = threadIdx.x;
    const int w = t >> 6, lane = t & 63;

    __shared__ float inv[H];
    {
        const float* p0 = psum + ((size_t)b * H + 2 * w) * NBLK;
        const float* p1 = psum + ((size_t)b * H + 2 * w + 1) * NBLK;
        float s0 = 0.f, s1 = 0.f;
        for (int c = lane; c < NBLK; c += 64) {
            s0 += p0[c];
            s1 += p1[c];
        }
        #pragma unroll
        for (int off = 1; off < 64; off <<= 1) {
            s0 += __shfl_xor(s0, off);
            s1 += __shfl_xor(s1, off);
        }
        if (lane == 0) {
            inv[2 * w]     = 1.0f / s0;
            inv[2 * w + 1] = 1.0f / s1;
        }
    }
    __syncthreads();

    float* p = att + (size_t)b * (E * H) + (size_t)blk * (EPB * H) + t * 8;
    float4 v0 = *(float4*)p;
    float4 v1 = *(float4*)(p + 4);
    v0.x *= inv[0]; v0.y *= inv[1]; v0.z *= inv[2]; v0.w *= inv[3];
    v1.x *= inv[4]; v1.y *= inv[5]; v1.z *= inv[6]; v1.w *= inv[7];
    *(float4*)p       = v0;
    *(float4*)(p + 4) = v1;
}

extern "C" void kernel_launch(void* const* d_in, const int* in_sizes, int n_in,
                              void* d_out, int out_size, void* d_ws, size_t ws_size,
                              hipStream_t stream)
{
    const float* x  = (const float*)d_in[0];
    const float* Qw = (const float*)d_in[1];
    const float* Qb = (const float*)d_in[2];
    const float* Kw = (const float*)d_in[3];
    const float* Kb = (const float*)d_in[4];
    const float* Vw = (const float*)d_in[5];
    const float* Vb = (const float*)d_in[6];
    const int*   edge = (const int*)d_in[7];

    float* out  = (float*)d_out;
    float* att  = out;                                // B*E*H
    float* vout = out + (size_t)B * E * H;            // B*N*DK*H

    char* w = (char*)d_ws;
    unsigned char* qws = (unsigned char*)w;                       // 5.12 MB fp8
    unsigned char* kws = qws + (size_t)B * N * DA;                // 5.12 MB fp8
    float* psum = (float*)(w + 2 * (size_t)B * N * DA);           // 80 KB

    hipLaunchKernelGGL(proj_mfma, dim3(TOTAL / 64), dim3(256), 0, stream,
                       x, Qw, Kw, Vw, Qb, Kb, Vb, qws, kws, vout);
    hipLaunchKernelGGL(gather_dot_sm, dim3(B, NBLK), dim3(256), 0, stream,
                       qws, kws, edge, att, psum);
    hipLaunchKernelGGL(softmax_norm, dim3(B, NBLK), dim3(256), 0, stream,
                       att, psum);
}